// Round 11
// baseline (506.581 us; speedup 1.0000x reference)
//
#include <hip/hip_runtime.h>
#include <math.h>

// Problem geometry (fixed by the reference)
#define BB 8
#define CC 256
#define HWSZ 36864            // floats per (b,c) slice
#define HALF 18432            // floats per half slice
#define H4 4608               // float4 per half slice
#define TPB 256
#define ITH 18                // float4 per thread (18*256 = 4608)
#define IT 36                 // float4 per thread, full slice (fallback kernels)
#define INTERNAL 16
#define NBLK 512              // 2 blocks/CU; LDS 2*76KB = 152KB <= 160KB
#define NSLICE 2048

typedef float f4 __attribute__((ext_vector_type(4)));

// =================== fused single-kernel (604 MB total traffic) ==========
// Block owns channel c = blk>>1, half h = blk&1. Per batch b:
//   A: global -> LDS (72 KB, thread-private slots) + sumsq partial
//      -> pbuf[b][c][h], release-increment cnt[b]
//   spin until cnt[b] == 512 (all co-resident: cooperative launch)
//   gate MLP (block-local, ~4k FLOP)
//   B: LDS -> scale -> nt-store. Input is read from HBM exactly once.
__global__ __launch_bounds__(TPB, 2) void se_fused_kernel(
    const float* __restrict__ in, float* __restrict__ out,
    float* __restrict__ pbuf,          // [BB][CC][2]
    unsigned int* __restrict__ cnt,    // [BB], zeroed per call
    const float* __restrict__ w_down, const float* __restrict__ b_down,
    const float* __restrict__ w_up, const float* __restrict__ b_up)
{
    const int blk = blockIdx.x;
    const int c   = blk >> 1;
    const int h   = blk & 1;
    const int tid = threadIdx.x;
    const int lane = tid & 63, wave = tid >> 6;

    __shared__ f4 buf[H4];             // 73728 B staging
    __shared__ float xs[CC];
    __shared__ float hs[INTERNAL];
    __shared__ float red[4];
    __shared__ float gsh;

    for (int b = 0; b < BB; ++b) {
        // ---- phase A: stream half-slice into LDS + sum of squares ----
        const f4* p = reinterpret_cast<const f4*>(
            in + (size_t)(b * CC + c) * HWSZ + (size_t)h * HALF);
        float acc = 0.f;
        #pragma unroll
        for (int i = 0; i < ITH; ++i) {
            f4 v = __builtin_nontemporal_load(p + tid + i * TPB);
            buf[tid + i * TPB] = v;    // thread-private slot, no sync needed
            acc += v.x * v.x + v.y * v.y + v.z * v.z + v.w * v.w;
        }
        for (int off = 32; off > 0; off >>= 1)
            acc += __shfl_down(acc, off, 64);
        if (lane == 0) red[wave] = acc;
        __syncthreads();
        if (tid == 0) {
            float tot = red[0] + red[1] + red[2] + red[3];
            __hip_atomic_store(&pbuf[(size_t)(b * CC + c) * 2 + h], tot,
                               __ATOMIC_RELAXED, __HIP_MEMORY_SCOPE_AGENT);
            __hip_atomic_fetch_add(&cnt[b], 1u, __ATOMIC_RELEASE,
                                   __HIP_MEMORY_SCOPE_AGENT);
        }

        // ---- spin: wait for all 512 half-partials of batch b ----
        if (tid == 0) {
            while (__hip_atomic_load(&cnt[b], __ATOMIC_RELAXED,
                                     __HIP_MEMORY_SCOPE_AGENT) < (unsigned)NBLK)
                __builtin_amdgcn_s_sleep(8);
            // acquire: order pbuf reads after the observed releases
            (void)__hip_atomic_load(&cnt[b], __ATOMIC_ACQUIRE,
                                    __HIP_MEMORY_SCOPE_AGENT);
        }
        __syncthreads();

        // ---- gate MLP ----
        {
            float s0 = __hip_atomic_load(&pbuf[(size_t)(b * CC + tid) * 2 + 0],
                                         __ATOMIC_RELAXED,
                                         __HIP_MEMORY_SCOPE_AGENT);
            float s1 = __hip_atomic_load(&pbuf[(size_t)(b * CC + tid) * 2 + 1],
                                         __ATOMIC_RELAXED,
                                         __HIP_MEMORY_SCOPE_AGENT);
            float g = sqrtf(s0 + s1);
            xs[tid] = g / (g + 1e-6f);
        }
        __syncthreads();
        {
            const int j = tid >> 4, l = tid & 15;   // 16 threads per hidden j
            const float* wr = w_down + j * CC;
            float a = 0.f;
            #pragma unroll
            for (int k = 0; k < CC / 16; ++k)
                a += xs[l + k * 16] * wr[l + k * 16];
            a += __shfl_down(a, 8, 16);
            a += __shfl_down(a, 4, 16);
            a += __shfl_down(a, 2, 16);
            a += __shfl_down(a, 1, 16);
            if (l == 0) hs[j] = fmaxf(a + b_down[j], 0.f);
        }
        __syncthreads();
        if (tid == 0) {
            float a = b_up[c];
            const float* wu = w_up + c * INTERNAL;
            #pragma unroll
            for (int j = 0; j < INTERNAL; ++j) a += hs[j] * wu[j];
            gsh = 1.f / (1.f + expf(-a));
        }
        __syncthreads();

        // ---- phase B: scale LDS-resident data, stream out ----
        const float gv = gsh;
        f4* po = reinterpret_cast<f4*>(
            out + (size_t)(b * CC + c) * HWSZ + (size_t)h * HALF);
        #pragma unroll
        for (int i = 0; i < ITH; ++i) {
            f4 v = buf[tid + i * TPB];
            v *= gv;
            __builtin_nontemporal_store(v, po + tid + i * TPB);
        }
        // buf slots are thread-private; xs/hs/red protected by the
        // __syncthreads chain in the next iteration's gate section.
        __syncthreads();
    }
}

// =================== fallback: proven R7 two-kernel path (144 us) ========
__global__ __launch_bounds__(TPB) void se_sumsq_kernel(
    const float* __restrict__ in, float* __restrict__ sumsq)
{
    const int bc = blockIdx.x;
    const f4* p = reinterpret_cast<const f4*>(in + (size_t)bc * HWSZ);
    float a0 = 0.f, a1 = 0.f, a2 = 0.f, a3 = 0.f;
    #pragma unroll
    for (int i = 0; i < IT; i += 4) {
        f4 v0 = p[threadIdx.x + (i + 0) * TPB];
        f4 v1 = p[threadIdx.x + (i + 1) * TPB];
        f4 v2 = p[threadIdx.x + (i + 2) * TPB];
        f4 v3 = p[threadIdx.x + (i + 3) * TPB];
        a0 += v0.x * v0.x + v0.y * v0.y + v0.z * v0.z + v0.w * v0.w;
        a1 += v1.x * v1.x + v1.y * v1.y + v1.z * v1.z + v1.w * v1.w;
        a2 += v2.x * v2.x + v2.y * v2.y + v2.z * v2.z + v2.w * v2.w;
        a3 += v3.x * v3.x + v3.y * v3.y + v3.z * v3.z + v3.w * v3.w;
    }
    float acc = (a0 + a1) + (a2 + a3);
    for (int off = 32; off > 0; off >>= 1)
        acc += __shfl_down(acc, off, 64);
    __shared__ float red[4];
    const int lane = threadIdx.x & 63, wave = threadIdx.x >> 6;
    if (lane == 0) red[wave] = acc;
    __syncthreads();
    if (threadIdx.x == 0)
        sumsq[bc] = red[0] + red[1] + red[2] + red[3];
}

__global__ __launch_bounds__(TPB) void se_scale_kernel(
    const float* __restrict__ in,
    const float* __restrict__ sumsq,
    const float* __restrict__ w_down, const float* __restrict__ b_down,
    const float* __restrict__ w_up, const float* __restrict__ b_up,
    float* __restrict__ out)
{
    const int s = (NSLICE - 1) - blockIdx.x;   // reverse order
    const int b = s >> 8;
    const int c = s & 255;
    const int tid = threadIdx.x;

    __shared__ float xs[CC];
    __shared__ float hs[INTERNAL];
    __shared__ float gsh;

    {
        float g = sqrtf(sumsq[(b << 8) + tid]);
        xs[tid] = g / (g + 1e-6f);
    }
    __syncthreads();
    {
        const int j = tid >> 4, l = tid & 15;
        const float* wr = w_down + j * CC;
        float a = 0.f;
        #pragma unroll
        for (int k = 0; k < CC / 16; ++k)
            a += xs[l + k * 16] * wr[l + k * 16];
        a += __shfl_down(a, 8, 16);
        a += __shfl_down(a, 4, 16);
        a += __shfl_down(a, 2, 16);
        a += __shfl_down(a, 1, 16);
        if (l == 0) hs[j] = fmaxf(a + b_down[j], 0.f);
    }
    __syncthreads();
    if (tid == 0) {
        float a = b_up[c];
        const float* wu = w_up + c * INTERNAL;
        #pragma unroll
        for (int j = 0; j < INTERNAL; ++j) a += hs[j] * wu[j];
        gsh = 1.f / (1.f + expf(-a));
    }
    __syncthreads();

    const float gv = gsh;
    const f4* pi = reinterpret_cast<const f4*>(in + (size_t)s * HWSZ);
    f4* po = reinterpret_cast<f4*>(out + (size_t)s * HWSZ);
    #pragma unroll
    for (int i = 0; i < IT; i += 4) {
        f4 v0 = __builtin_nontemporal_load(pi + tid + (i + 0) * TPB);
        f4 v1 = __builtin_nontemporal_load(pi + tid + (i + 1) * TPB);
        f4 v2 = __builtin_nontemporal_load(pi + tid + (i + 2) * TPB);
        f4 v3 = __builtin_nontemporal_load(pi + tid + (i + 3) * TPB);
        v0 *= gv; v1 *= gv; v2 *= gv; v3 *= gv;
        __builtin_nontemporal_store(v0, po + tid + (i + 0) * TPB);
        __builtin_nontemporal_store(v1, po + tid + (i + 1) * TPB);
        __builtin_nontemporal_store(v2, po + tid + (i + 2) * TPB);
        __builtin_nontemporal_store(v3, po + tid + (i + 3) * TPB);
    }
}

extern "C" void kernel_launch(void* const* d_in, const int* in_sizes, int n_in,
                              void* d_out, int out_size, void* d_ws, size_t ws_size,
                              hipStream_t stream) {
    const float* inputs = (const float*)d_in[0];   // [B, C, H, W]
    const float* w_down = (const float*)d_in[1];   // [16, 256]
    const float* b_down = (const float*)d_in[2];   // [16]
    const float* w_up   = (const float*)d_in[3];   // [256, 16]
    const float* b_up   = (const float*)d_in[4];   // [256]
    float* out = (float*)d_out;

    float* pbuf       = (float*)d_ws;                    // BB*CC*2 floats
    unsigned int* cnt = (unsigned int*)(pbuf + BB * CC * 2);  // BB uints

    // zero per-batch arrival counters every call (graph-replay safe)
    hipMemsetAsync(cnt, 0, BB * sizeof(unsigned int), stream);

    void* args[] = { (void*)&inputs, (void*)&out, (void*)&pbuf, (void*)&cnt,
                     (void*)&w_down, (void*)&b_down, (void*)&w_up, (void*)&b_up };
    hipError_t err = hipLaunchCooperativeKernel(
        reinterpret_cast<void*>(se_fused_kernel),
        dim3(NBLK), dim3(TPB), args, 0, stream);

    if (err != hipSuccess) {
        // deterministic fallback: proven R7 two-kernel path
        float* sumsq = pbuf;   // reuse ws (2048 floats)
        se_sumsq_kernel<<<NSLICE, TPB, 0, stream>>>(inputs, sumsq);
        se_scale_kernel<<<NSLICE, TPB, 0, stream>>>(inputs, sumsq,
                                                    w_down, b_down,
                                                    w_up, b_up, out);
    }
}

// Round 12
// 144.670 us; speedup vs baseline: 3.5016x; 3.5016x over previous
//
#include <hip/hip_runtime.h>
#include <math.h>

// Problem geometry (fixed by the reference)
#define BB 8
#define CC 256
#define HWSZ 36864            // floats per (b,c) slice
#define TPB 256
#define IT 36                 // float4 per thread per slice
#define INTERNAL 16
#define NSLICE 2048
#define CHUNK 512             // slices per chunk = 2 batches = 75.5 MB

typedef float f4 __attribute__((ext_vector_type(4)));

// ---- sumsq for one slice (caching loads: want L3 residency for scale) ----
__device__ __forceinline__ void do_sumsq(const float* __restrict__ in,
                                         float* __restrict__ sumsq,
                                         int s, int tid)
{
    const f4* p = reinterpret_cast<const f4*>(in + (size_t)s * HWSZ);
    float a0 = 0.f, a1 = 0.f, a2 = 0.f, a3 = 0.f;
    #pragma unroll
    for (int i = 0; i < IT; i += 4) {
        f4 v0 = p[tid + (i + 0) * TPB];
        f4 v1 = p[tid + (i + 1) * TPB];
        f4 v2 = p[tid + (i + 2) * TPB];
        f4 v3 = p[tid + (i + 3) * TPB];
        a0 += v0.x * v0.x + v0.y * v0.y + v0.z * v0.z + v0.w * v0.w;
        a1 += v1.x * v1.x + v1.y * v1.y + v1.z * v1.z + v1.w * v1.w;
        a2 += v2.x * v2.x + v2.y * v2.y + v2.z * v2.z + v2.w * v2.w;
        a3 += v3.x * v3.x + v3.y * v3.y + v3.z * v3.z + v3.w * v3.w;
    }
    float acc = (a0 + a1) + (a2 + a3);
    for (int off = 32; off > 0; off >>= 1)
        acc += __shfl_down(acc, off, 64);

    __shared__ float red[4];
    const int lane = tid & 63, wave = tid >> 6;
    if (lane == 0) red[wave] = acc;
    __syncthreads();
    if (tid == 0)
        sumsq[s] = red[0] + red[1] + red[2] + red[3];
}

// ---- gate MLP + streaming scale for one slice (L3-hot input) ----
__device__ __forceinline__ void do_scale(const float* __restrict__ in,
                                         float* __restrict__ out,
                                         const float* __restrict__ sumsq,
                                         const float* __restrict__ w_down,
                                         const float* __restrict__ b_down,
                                         const float* __restrict__ w_up,
                                         const float* __restrict__ b_up,
                                         int s, int tid)
{
    const int b = s >> 8;
    const int c = s & 255;

    __shared__ float xs[CC];
    __shared__ float hs[INTERNAL];
    __shared__ float gsh;

    {
        float g = sqrtf(sumsq[(b << 8) + tid]);
        xs[tid] = g / (g + 1e-6f);
    }
    __syncthreads();
    {
        const int j = tid >> 4, l = tid & 15;   // 16 threads per hidden j
        const float* wr = w_down + j * CC;
        float a = 0.f;
        #pragma unroll
        for (int k = 0; k < CC / 16; ++k)
            a += xs[l + k * 16] * wr[l + k * 16];
        a += __shfl_down(a, 8, 16);
        a += __shfl_down(a, 4, 16);
        a += __shfl_down(a, 2, 16);
        a += __shfl_down(a, 1, 16);
        if (l == 0) hs[j] = fmaxf(a + b_down[j], 0.f);
    }
    __syncthreads();
    if (tid == 0) {
        float a = b_up[c];
        const float* wu = w_up + c * INTERNAL;
        #pragma unroll
        for (int j = 0; j < INTERNAL; ++j) a += hs[j] * wu[j];
        gsh = 1.f / (1.f + expf(-a));
    }
    __syncthreads();

    const float gv = gsh;
    const f4* pi = reinterpret_cast<const f4*>(in + (size_t)s * HWSZ);
    f4* po = reinterpret_cast<f4*>(out + (size_t)s * HWSZ);
    #pragma unroll
    for (int i = 0; i < IT; i += 4) {
        f4 v0 = __builtin_nontemporal_load(pi + tid + (i + 0) * TPB);
        f4 v1 = __builtin_nontemporal_load(pi + tid + (i + 1) * TPB);
        f4 v2 = __builtin_nontemporal_load(pi + tid + (i + 2) * TPB);
        f4 v3 = __builtin_nontemporal_load(pi + tid + (i + 3) * TPB);
        v0 *= gv; v1 *= gv; v2 *= gv; v3 *= gv;
        __builtin_nontemporal_store(v0, po + tid + (i + 0) * TPB);
        __builtin_nontemporal_store(v1, po + tid + (i + 1) * TPB);
        __builtin_nontemporal_store(v2, po + tid + (i + 2) * TPB);
        __builtin_nontemporal_store(v3, po + tid + (i + 3) * TPB);
    }
}

// ---- pipelined pair: scale(chunk j-1) || sumsq(chunk j) ----
// Plain launches only (no in-kernel global sync — R4/R5/R8/R11 all showed
// any such sync throttles streaming 3-7x on this chip).
__global__ __launch_bounds__(TPB) void se_pipe_kernel(
    const float* __restrict__ in, float* __restrict__ out,
    float* __restrict__ sumsq,
    const float* __restrict__ w_down, const float* __restrict__ b_down,
    const float* __restrict__ w_up, const float* __restrict__ b_up,
    int scale_base, int sum_base)
{
    const int idx = blockIdx.x;
    const int tid = threadIdx.x;
    const bool both = (scale_base >= 0) && (sum_base >= 0);

    if (both) {
        if (idx < CHUNK)
            do_scale(in, out, sumsq, w_down, b_down, w_up, b_up,
                     scale_base + idx, tid);
        else
            do_sumsq(in, sumsq, sum_base + (idx - CHUNK), tid);
    } else if (sum_base >= 0) {
        do_sumsq(in, sumsq, sum_base + idx, tid);
    } else {
        do_scale(in, out, sumsq, w_down, b_down, w_up, b_up,
                 scale_base + idx, tid);
    }
}

extern "C" void kernel_launch(void* const* d_in, const int* in_sizes, int n_in,
                              void* d_out, int out_size, void* d_ws, size_t ws_size,
                              hipStream_t stream) {
    const float* inputs = (const float*)d_in[0];   // [B, C, H, W]
    const float* w_down = (const float*)d_in[1];   // [16, 256]
    const float* b_down = (const float*)d_in[2];   // [16]
    const float* w_up   = (const float*)d_in[3];   // [256, 16]
    const float* b_up   = (const float*)d_in[4];   // [256]
    float* out   = (float*)d_out;
    float* sumsq = (float*)d_ws;                   // 2048 floats

    // prologue: sumsq(chunk 0)
    se_pipe_kernel<<<CHUNK, TPB, 0, stream>>>(
        inputs, out, sumsq, w_down, b_down, w_up, b_up, -1, 0);
    // steady state: scale(chunk j-1) [L3-hot] + sumsq(chunk j) [fresh HBM]
    for (int j = 1; j < NSLICE / CHUNK; ++j)
        se_pipe_kernel<<<2 * CHUNK, TPB, 0, stream>>>(
            inputs, out, sumsq, w_down, b_down, w_up, b_up,
            (j - 1) * CHUNK, j * CHUNK);
    // epilogue: scale(last chunk)
    se_pipe_kernel<<<CHUNK, TPB, 0, stream>>>(
        inputs, out, sumsq, w_down, b_down, w_up, b_up,
        NSLICE - CHUNK, -1);
}